// Round 3
// baseline (877.694 us; speedup 1.0000x reference)
//
#include <hip/hip_runtime.h>
#include <hip/hip_bf16.h>
#include <math.h>

typedef __hip_bfloat16 bf16;
typedef unsigned int u32;
typedef __attribute__((ext_vector_type(8))) short short8;   // 8 x bf16 MFMA A/B frag
typedef __attribute__((ext_vector_type(4))) float f32x4;    // MFMA C/D frag

// MFMA 16x16x32 bf16 verified layouts (learn_hip m89/m91):
//   A-frag: A[m = lane&15][k = (lane>>4)*8 + j]
//   B-frag: B[k = (lane>>4)*8 + j][n = lane&15]
//   C/D   : col = lane&15, row = (lane>>4)*4 + reg

#define ATT_LDK 72
#define PS_LD  72     // staging stride: 144B row (16B-aligned for b128)

typedef __attribute__((address_space(3))) u32 lds_u32;
typedef const __attribute__((address_space(1))) u32 glb_u32;
static __device__ __forceinline__ void g2l16(const void* g, void* l) {
    __builtin_amdgcn_global_load_lds((glb_u32*)g, (lds_u32*)l, 16, 0, 0);
}

static __device__ __forceinline__ unsigned short bf16bits(float f) {
    bf16 h = __float2bfloat16(f);
    return *(unsigned short*)&h;
}

// ---------------------------------------------------------------------------
// Weight prep: W fp32 [K=1024, N=1024] -> Wt bf16 [N, K]  (20 matrices)
// ---------------------------------------------------------------------------
__global__ __launch_bounds__(256) void wprep_kernel(
    const float* __restrict__ wq, const float* __restrict__ wk,
    const float* __restrict__ wv, const float* __restrict__ wo,
    const float* __restrict__ wf, bf16* __restrict__ wt_all)
{
    __shared__ bf16 tile[64][ATT_LDK];
    const int z = blockIdx.z;
    const int l = z / 5, f = z % 5;
    const float* src = (f == 0) ? wq : (f == 1) ? wk : (f == 2) ? wv : (f == 3) ? wo : wf;
    src += (size_t)l * 1024 * 1024;
    bf16* dst = wt_all + ((size_t)l * 5 + f) * 1024 * 1024;

    const int k0 = blockIdx.x * 64, n0 = blockIdx.y * 64;
    const int t = threadIdx.x;
#pragma unroll
    for (int rr = 0; rr < 4; ++rr) {
        int slot = t + rr * 256;
        int r = slot >> 4, c = slot & 15;
        float4 v = *(const float4*)(src + (size_t)(k0 + r) * 1024 + n0 + c * 4);
        tile[c * 4 + 0][r] = __float2bfloat16(v.x);
        tile[c * 4 + 1][r] = __float2bfloat16(v.y);
        tile[c * 4 + 2][r] = __float2bfloat16(v.z);
        tile[c * 4 + 3][r] = __float2bfloat16(v.w);
    }
    __syncthreads();
#pragma unroll
    for (int rr = 0; rr < 2; ++rr) {
        int slot = t + rr * 256;
        int n = slot >> 3, c = slot & 7;
        *(uint4*)(dst + (size_t)(n0 + n) * 1024 + k0 + c * 8) = *(const uint4*)&tile[n][c * 8];
    }
}

// stacked qkv bias: bqkv[l][3072] = [bq[l] | bk[l] | bv[l]]
// + PE rate table: rate[d] = (float)pow(10000., 2*floor_m(d)/1024)  (1024 entries,
//   hoisted out of pe_kernel where it was recomputed 1M times in f64; bit-identical)
__global__ void bias_stack_kernel(const float* __restrict__ bq, const float* __restrict__ bk,
                                  const float* __restrict__ bv, float* __restrict__ bqkv,
                                  float* __restrict__ rate)
{
    int i = blockIdx.x * 256 + threadIdx.x;
    if (i < 1024) {
        int m = (i < 512) ? i : (i - 512);
        float ex = (float)(2 * m) * (1.0f / 1024.0f);
        rate[i] = (float)pow(10000.0, (double)ex);
    }
    if (i < 4 * 3072) {
        int l = i / 3072, c = i % 3072;
        int fam = c >> 10, cc = c & 1023;
        const float* s = (fam == 0) ? bq : (fam == 1) ? bk : bv;
        bqkv[i] = s[l * 1024 + cc];
    }
}

// ---------------------------------------------------------------------------
// PE table: pe[s][d]. rate[] precomputed (same bits); f64 sin/cos kept.
// ---------------------------------------------------------------------------
__global__ __launch_bounds__(256) void pe_kernel(const float* __restrict__ rate,
                                                 float* __restrict__ pe)
{
    int idx = blockIdx.x * 256 + threadIdx.x;     // 0 .. 256K-1
    int d0 = (idx & 255) * 4;
    int s = idx >> 8;
    float out[4];
#pragma unroll
    for (int j = 0; j < 4; ++j) {
        int d = d0 + j;
        float ang = (float)s * rate[d];               // f32 rounding matches ref
        double a = (double)ang;
        out[j] = (d < 512) ? (float)sin(a) : (float)cos(a);
    }
    *(float4*)(pe + (size_t)s * 1024 + d0) = *(float4*)out;
}

// ---------------------------------------------------------------------------
// Embedding gather + PE add.
// ---------------------------------------------------------------------------
__global__ __launch_bounds__(256) void embed_kernel(
    const int* __restrict__ x, const float* __restrict__ emb,
    const float* __restrict__ pe,
    float* __restrict__ hf, bf16* __restrict__ hb)
{
    int idx = blockIdx.x * 256 + threadIdx.x;     // 0 .. 1M-1
    int d0 = (idx & 255) * 4;
    int row = idx >> 8;                           // b*1024 + s
    int s = row & 1023;
    int tok = x[row];
    float4 e = *(const float4*)(emb + (size_t)tok * 1024 + d0);
    float4 p = *(const float4*)(pe + (size_t)s * 1024 + d0);
    float out[4] = {e.x * 32.0f + p.x, e.y * 32.0f + p.y,
                    e.z * 32.0f + p.z, e.w * 32.0f + p.w};
    *(float4*)(hf + (size_t)row * 1024 + d0) = *(float4*)out;
    unsigned short pk[4];
#pragma unroll
    for (int j = 0; j < 4; ++j) pk[j] = bf16bits(out[j]);
    *(uint2*)(hb + (size_t)row * 1024 + d0) = *(uint2*)pk;
}

// ---------------------------------------------------------------------------
// GEMM 128x128, BK=32, 4 waves. global_load_lds + XOR slot swizzle.
// Double-buffered; stage k0+32 issued right after the single barrier.
// Epilogues: bf16 via LDS->uint4 (Cb); V-block transposed write into Vt
// (n0>=2048 && VtOut) -- fuses the old transpose_v kernel into the QKV GEMM.
// (8-phase 256-tile port regressed at this shape: grid 192 < 256 CUs + short
//  K=1024 amortization — reverted to this known-good structure.)
// ---------------------------------------------------------------------------
__global__ __launch_bounds__(256, 3) void gemm_bt_kernel(
    const bf16* __restrict__ A, const bf16* __restrict__ Bt,
    const float* __restrict__ bias,
    bf16* __restrict__ Cb, bf16* __restrict__ VtOut,
    int M, int N, int K)
{
    __shared__ bf16 As[2][128 * 32];
    __shared__ bf16 Bs[2][128 * 32];
    __shared__ bf16 Cst[4][16 * PS_LD];
    const int t = threadIdx.x;
    const int lane = t & 63, wave = t >> 6;
    const int wr = wave >> 1, wc = wave & 1;
    const int lidx = lane & 15, quad = lane >> 4;
    const int m0 = blockIdx.x * 128, n0 = blockIdx.y * 128;

    f32x4 acc[4][4];
#pragma unroll
    for (int i = 0; i < 4; ++i)
#pragma unroll
        for (int j = 0; j < 4; ++j) acc[i][j] = (f32x4){0.f, 0.f, 0.f, 0.f};

    const int r0 = wave * 32;
    const int rloc = lane >> 2;
    const int csw = ((lane & 3) ^ ((lane >> 3) & 3)) * 8;
    const bf16* Abase = A  + (size_t)(m0 + r0 + rloc) * K + csw;
    const bf16* Bbase = Bt + (size_t)(n0 + r0 + rloc) * K + csw;
    const int lofs = r0 * 32;
    const int aslot = (quad ^ ((lidx >> 1) & 3)) * 8;

    g2l16(Abase,                  &As[0][lofs]);
    g2l16(Abase + 16 * (size_t)K, &As[0][lofs + 16 * 32]);
    g2l16(Bbase,                  &Bs[0][lofs]);
    g2l16(Bbase + 16 * (size_t)K, &Bs[0][lofs + 16 * 32]);

    for (int k0 = 0; k0 < K; k0 += 32) {
        __syncthreads();
        const int cur = (k0 >> 5) & 1;
        if (k0 + 32 < K) {
            const int kn = k0 + 32;
            g2l16(Abase + kn,                  &As[cur ^ 1][lofs]);
            g2l16(Abase + kn + 16 * (size_t)K, &As[cur ^ 1][lofs + 16 * 32]);
            g2l16(Bbase + kn,                  &Bs[cur ^ 1][lofs]);
            g2l16(Bbase + kn + 16 * (size_t)K, &Bs[cur ^ 1][lofs + 16 * 32]);
        }

        short8 af[4], bfr[4];
#pragma unroll
        for (int i = 0; i < 4; ++i)
            af[i] = *(const short8*)(&As[cur][(wr * 64 + i * 16 + lidx) * 32 + aslot]);
#pragma unroll
        for (int j = 0; j < 4; ++j)
            bfr[j] = *(const short8*)(&Bs[cur][(wc * 64 + j * 16 + lidx) * 32 + aslot]);
#pragma unroll
        for (int i = 0; i < 4; ++i)
#pragma unroll
            for (int j = 0; j < 4; ++j)
                acc[i][j] = __builtin_amdgcn_mfma_f32_16x16x32_bf16(af[i], bfr[j], acc[i][j], 0, 0, 0);
    }

    float bvj[4];
#pragma unroll
    for (int j = 0; j < 4; ++j)
        bvj[j] = bias ? bias[n0 + wc * 64 + j * 16 + lidx] : 0.0f;

    if (VtOut && n0 >= 2048) {
        const int bidx = m0 >> 10;
        const int s_base = (m0 & 1023) + wr * 64 + quad * 4;
        const int d_base = (n0 - 2048) + wc * 64;
#pragma unroll
        for (int i = 0; i < 4; ++i)
#pragma unroll
            for (int j = 0; j < 4; ++j) {
                unsigned short pk[4];
#pragma unroll
                for (int r = 0; r < 4; ++r)
                    pk[r] = bf16bits(acc[i][j][r] + bvj[j]);
                bf16* dst = VtOut + ((size_t)bidx * 1024 + d_base + j * 16 + lidx) * 1024
                            + s_base + i * 16;
                *(uint2*)dst = *(const uint2*)pk;
            }
    } else {
        const int row16 = lane >> 2, c4 = lane & 3;
#pragma unroll
        for (int i = 0; i < 4; ++i) {
#pragma unroll
            for (int j = 0; j < 4; ++j)
#pragma unroll
                for (int r = 0; r < 4; ++r)
                    Cst[wave][(quad * 4 + r) * PS_LD + j * 16 + lidx] =
                        __float2bfloat16(acc[i][j][r] + bvj[j]);
            bf16* dst = Cb + (size_t)(m0 + wr * 64 + i * 16 + row16) * N + n0 + wc * 64;
            const bf16* srcr = &Cst[wave][row16 * PS_LD];
#pragma unroll
            for (int h = 0; h < 2; ++h)
                *(uint4*)(dst + (c4 + 4 * h) * 8) = *(const uint4*)(srcr + (c4 + 4 * h) * 8);
        }
    }
}

// ---------------------------------------------------------------------------
// GEMM 64x128 tile (fp32 out) for N=1024 projections.
// Double-buffered staging + fused residual add: Cf = A@Bt + bias + resid.
// ---------------------------------------------------------------------------
__global__ __launch_bounds__(256, 4) void gemm64_kernel(
    const bf16* __restrict__ A, const bf16* __restrict__ Bt,
    const float* __restrict__ bias, const float* __restrict__ resid,
    float* __restrict__ Cf,
    int M, int N, int K)
{
    __shared__ bf16 As[2][64 * 32];
    __shared__ bf16 Bs[2][128 * 32];
    const int t = threadIdx.x;
    const int lane = t & 63, wave = t >> 6;
    const int wr = wave >> 1, wc = wave & 1;
    const int lidx = lane & 15, quad = lane >> 4;
    const int m0 = blockIdx.x * 64, n0 = blockIdx.y * 128;

    f32x4 acc[2][4];
#pragma unroll
    for (int i = 0; i < 2; ++i)
#pragma unroll
        for (int j = 0; j < 4; ++j) acc[i][j] = (f32x4){0.f, 0.f, 0.f, 0.f};

    const int rloc = lane >> 2;
    const int csw = ((lane & 3) ^ ((lane >> 3) & 3)) * 8;
    const bf16* Abase = A  + (size_t)(m0 + wave * 16 + rloc) * K + csw;
    const bf16* Bbase = Bt + (size_t)(n0 + wave * 32 + rloc) * K + csw;
    const int alofs = wave * 16 * 32;
    const int blofs = wave * 32 * 32;
    const int aslot = (quad ^ ((lidx >> 1) & 3)) * 8;

    g2l16(Abase,                  &As[0][alofs]);
    g2l16(Bbase,                  &Bs[0][blofs]);
    g2l16(Bbase + 16 * (size_t)K, &Bs[0][blofs + 16 * 32]);

    for (int k0 = 0; k0 < K; k0 += 32) {
        __syncthreads();
        const int cur = (k0 >> 5) & 1;
        if (k0 + 32 < K) {
            const int kn = k0 + 32;
            g2l16(Abase + kn,                  &As[cur ^ 1][alofs]);
            g2l16(Bbase + kn,                  &Bs[cur ^ 1][blofs]);
            g2l16(Bbase + kn + 16 * (size_t)K, &Bs[cur ^ 1][blofs + 16 * 32]);
        }

        short8 af[2], bfr[4];
#pragma unroll
        for (int i = 0; i < 2; ++i)
            af[i] = *(const short8*)(&As[cur][(wr * 32 + i * 16 + lidx) * 32 + aslot]);
#pragma unroll
        for (int j = 0; j < 4; ++j)
            bfr[j] = *(const short8*)(&Bs[cur][(wc * 64 + j * 16 + lidx) * 32 + aslot]);
#pragma unroll
        for (int i = 0; i < 2; ++i)
#pragma unroll
            for (int j = 0; j < 4; ++j)
                acc[i][j] = __builtin_amdgcn_mfma_f32_16x16x32_bf16(af[i], bfr[j], acc[i][j], 0, 0, 0);
    }

#pragma unroll
    for (int i = 0; i < 2; ++i)
#pragma unroll
        for (int j = 0; j < 4; ++j) {
            int col = n0 + wc * 64 + j * 16 + lidx;
            float bv = bias[col];
#pragma unroll
            for (int r = 0; r < 4; ++r) {
                int rowg = m0 + wr * 32 + i * 16 + quad * 4 + r;
                Cf[(size_t)rowg * N + col] =
                    acc[i][j][r] + bv + resid[(size_t)rowg * N + col];
            }
        }
}

// ---------------------------------------------------------------------------
// Flash attention, no-max softmax. Per block: (b,h) x 128 q-rows, 8 waves.
// Changes this round (bit-identical values & order):
//   - mask premultiplied by -1e9 and hoisted to LDS once per block (was an
//     HBM/L2 read per kv-tile per lane).
//   - Vs LDS staging DROPPED: V fragments read direct from L2-resident Vt
//     (128 KB per (b,h), reused by 8 q-blocks) per learn_hip m169 ("don't
//     stage what L2-fits"). Halves barrier-guarded staging; LDS 50->38 KB.
// ---------------------------------------------------------------------------
__global__ __launch_bounds__(512, 4) void attention_kernel(
    const bf16* __restrict__ QKV,    // [4096, 3072] = [q|k|-]
    const bf16* __restrict__ Vt,     // [b][d(1024)][s(1024)]
    const float* __restrict__ mask,  // [4,1024]
    bf16* __restrict__ ctx)          // [4096, 1024]
{
    __shared__ bf16 Ks[2][64 * 64];
    __shared__ bf16 Ps[8][16 * PS_LD];
    __shared__ float Ms[1024];

    const int t = threadIdx.x, lane = t & 63, wave = t >> 6;
    const int quad = lane >> 4, lidx = lane & 15;
    const int b = blockIdx.x >> 4, hh = blockIdx.x & 15;
    const int q0 = blockIdx.y * 128 + wave * 16;

    const int r8 = lane >> 3;
    const int gc = ((lane & 7) ^ r8) * 8;
    const bf16* kg0 = QKV + (size_t)(b * 1024 + wave * 8 + r8) * 3072 + 1024 + hh * 64 + gc;
    const int lofs = wave * 8 * 64;

    // mask -> LDS, premultiplied (same f32 mult as before; covered by first sync)
    Ms[t]       = mask[b * 1024 + t] * -1e9f;
    Ms[t + 512] = mask[b * 1024 + t + 512] * -1e9f;

    short8 qf[2];
    {
        const bf16* qp = QKV + (size_t)(b * 1024 + q0 + lidx) * 3072 + hh * 64;
        qf[0] = *(const short8*)(qp + quad * 8);
        qf[1] = *(const short8*)(qp + 32 + quad * 8);
    }

    // V direct-from-global base for this lane's B-fragment rows
    const bf16* vbase = Vt + (size_t)(b * 1024 + hh * 64) * 1024;

    f32x4 Oacc[4];
#pragma unroll
    for (int nt = 0; nt < 4; ++nt) Oacc[nt] = (f32x4){0.f, 0.f, 0.f, 0.f};
    float psum[4] = {0.f, 0.f, 0.f, 0.f};

    const int fslot = lidx & 7;

    g2l16(kg0, &Ks[0][lofs]);

    for (int kt = 0; kt < 16; ++kt) {
        __syncthreads();
        const int cur = kt & 1;
        if (kt < 15)
            g2l16(kg0 + (size_t)(kt + 1) * 64 * 3072, &Ks[cur ^ 1][lofs]);

        f32x4 sacc[4];
#pragma unroll
        for (int nt = 0; nt < 4; ++nt) sacc[nt] = (f32x4){0.f, 0.f, 0.f, 0.f};
#pragma unroll
        for (int kk = 0; kk < 2; ++kk)
#pragma unroll
            for (int nt = 0; nt < 4; ++nt) {
                short8 kf = *(const short8*)(&Ks[cur][(nt * 16 + lidx) * 64 + (((kk * 4 + quad) ^ fslot) * 8)]);
                sacc[nt] = __builtin_amdgcn_mfma_f32_16x16x32_bf16(qf[kk], kf, sacc[nt], 0, 0, 0);
            }

#pragma unroll
        for (int nt = 0; nt < 4; ++nt) {
            float mv = Ms[kt * 64 + nt * 16 + lidx];
#pragma unroll
            for (int r = 0; r < 4; ++r) {
                float p = __expf(sacc[nt][r] * 0.125f + mv);
                sacc[nt][r] = p;
                psum[r] += p;
            }
        }

#pragma unroll
        for (int nt = 0; nt < 4; ++nt)
#pragma unroll
            for (int r = 0; r < 4; ++r)
                Ps[wave][(quad * 4 + r) * PS_LD + nt * 16 + lidx] = __float2bfloat16(sacc[nt][r]);

#pragma unroll
        for (int kk = 0; kk < 2; ++kk) {
            short8 pf = *(const short8*)(&Ps[wave][lidx * PS_LD + kk * 32 + quad * 8]);
#pragma unroll
            for (int nt = 0; nt < 4; ++nt) {
                // same values the old Vs path delivered (swizzle canceled):
                // Vt row (hh*64 + nt*16 + lidx), cols kt*64 + kk*32 + quad*8 ..+7
                short8 vf = *(const short8*)(vbase + (size_t)(nt * 16 + lidx) * 1024
                                             + kt * 64 + kk * 32 + quad * 8);
                Oacc[nt] = __builtin_amdgcn_mfma_f32_16x16x32_bf16(pf, vf, Oacc[nt], 0, 0, 0);
            }
        }
    }

#pragma unroll
    for (int off = 1; off < 16; off <<= 1)
#pragma unroll
        for (int r = 0; r < 4; ++r)
            psum[r] += __shfl_xor(psum[r], off, 64);
    float linv[4];
#pragma unroll
    for (int r = 0; r < 4; ++r) linv[r] = 1.0f / psum[r];

#pragma unroll
    for (int nt = 0; nt < 4; ++nt)
#pragma unroll
        for (int r = 0; r < 4; ++r)
            Ps[wave][(quad * 4 + r) * PS_LD + nt * 16 + lidx] = __float2bfloat16(Oacc[nt][r] * linv[r]);

    const int row16 = lane >> 2, c4 = lane & 3;
    bf16* dst = ctx + (size_t)(b * 1024 + q0 + row16) * 1024 + hh * 64;
    const bf16* srcr = &Ps[wave][row16 * PS_LD];
#pragma unroll
    for (int h = 0; h < 2; ++h)
        *(uint4*)(dst + (c4 + 4 * h) * 8) = *(const uint4*)(srcr + (c4 + 4 * h) * 8);
}

// ---------------------------------------------------------------------------
// h = LN(x) * g + b.  x already contains residual+delta (fused in gemm64).
// ---------------------------------------------------------------------------
__global__ __launch_bounds__(256) void add_ln_kernel(
    const float* __restrict__ x,
    const float* __restrict__ g, const float* __restrict__ b,
    float* __restrict__ outf, bf16* __restrict__ outb)
{
    __shared__ float red[4];
    const int row = blockIdx.x;
    const int t = threadIdx.x;
    const int c0 = t * 4;
    float4 xv = *(const float4*)(x + (size_t)row * 1024 + c0);
    float v[4] = {xv.x, xv.y, xv.z, xv.w};
    float s = v[0] + v[1] + v[2] + v[3];
#pragma unroll
    for (int off = 1; off < 64; off <<= 1) s += __shfl_xor(s, off, 64);
    if ((t & 63) == 0) red[t >> 6] = s;
    __syncthreads();
    float mean = (red[0] + red[1] + red[2] + red[3]) * (1.0f / 1024.0f);
    float sq = 0.f;
#pragma unroll
    for (int i = 0; i < 4; ++i) { float d = v[i] - mean; sq += d * d; }
#pragma unroll
    for (int off = 1; off < 64; off <<= 1) sq += __shfl_xor(sq, off, 64);
    __syncthreads();
    if ((t & 63) == 0) red[t >> 6] = sq;
    __syncthreads();
    float var = (red[0] + red[1] + red[2] + red[3]) * (1.0f / 1024.0f);
    float rs = rsqrtf(var + 1e-6f);
    float4 gv = *(const float4*)(g + c0);
    float4 bv = *(const float4*)(b + c0);
    float gg[4] = {gv.x, gv.y, gv.z, gv.w}, bb[4] = {bv.x, bv.y, bv.z, bv.w};
    float o[4];
    unsigned short pk[4];
#pragma unroll
    for (int i = 0; i < 4; ++i) {
        o[i] = (v[i] - mean) * rs * gg[i] + bb[i];
        pk[i] = bf16bits(o[i]);
    }
    *(float4*)(outf + (size_t)row * 1024 + c0) = *(float4*)o;
    *(uint2*)(outb + (size_t)row * 1024 + c0) = *(uint2*)pk;
}

// ---------------------------------------------------------------------------
extern "C" void kernel_launch(void* const* d_in, const int* in_sizes, int n_in,
                              void* d_out, int out_size, void* d_ws, size_t ws_size,
                              hipStream_t stream)
{
    const int*   x    = (const int*)d_in[0];
    const float* mask = (const float*)d_in[1];
    const float* emb  = (const float*)d_in[2];
    const float* wq   = (const float*)d_in[3];
    const float* bq   = (const float*)d_in[4];
    const float* wk   = (const float*)d_in[5];
    const float* bk   = (const float*)d_in[6];
    const float* wv   = (const float*)d_in[7];
    const float* bv   = (const float*)d_in[8];
    const float* wo   = (const float*)d_in[9];
    const float* bo   = (const float*)d_in[10];
    const float* wf   = (const float*)d_in[11];
    const float* bfp  = (const float*)d_in[12];
    const float* g1   = (const float*)d_in[13];
    const float* b1   = (const float*)d_in[14];
    const float* g2   = (const float*)d_in[15];
    const float* b2   = (const float*)d_in[16];

    char* ws = (char*)d_ws;
    float* h_f  = (float*)ws;                 ws += 4096ull * 1024 * 4;   // 16 MB
    bf16*  h_b  = (bf16*)ws;                  ws += 4096ull * 1024 * 2;   //  8 MB
    bf16*  qkv  = (bf16*)ws;                  ws += 4096ull * 3072 * 2;   // 24 MB
    bf16*  vt   = (bf16*)ws;                  ws += 4096ull * 1024 * 2;   //  8 MB
    bf16*  ctx  = (bf16*)ws;                  ws += 4096ull * 1024 * 2;   //  8 MB
    bf16*  wt   = (bf16*)ws;                  ws += 20ull * 1024 * 1024 * 2; // 40 MB
    float* pe   = (float*)ws;                 ws += 1024ull * 1024 * 4;   //  4 MB
    float* bqkv = (float*)ws;                 ws += 4ull * 3072 * 4;
    float* rate = (float*)ws;                 ws += 1024ull * 4;
    float* delta = (float*)qkv;  // fp32 GEMM out, alias of qkv (dead by then)

    wprep_kernel<<<dim3(16, 16, 20), 256, 0, stream>>>(wq, wk, wv, wo, wf, wt);
    bias_stack_kernel<<<dim3(48), 256, 0, stream>>>(bq, bk, bv, bqkv, rate);
    pe_kernel<<<dim3(1024), 256, 0, stream>>>(rate, pe);
    embed_kernel<<<dim3(4096), 256, 0, stream>>>(x, emb, pe, h_f, h_b);

    for (int l = 0; l < 4; ++l) {
        bf16* wt_l = wt + (size_t)l * 5 * 1024 * 1024;
        // QKV: Q,K -> qkv cols [0,2048); V -> vt transposed (fused)
        gemm_bt_kernel<<<dim3(32, 24), 256, 0, stream>>>(
            h_b, wt_l, bqkv + l * 3072, qkv, vt, 4096, 3072, 1024);
        attention_kernel<<<dim3(64, 8), 512, 0, stream>>>(qkv, vt, mask, ctx);
        // delta = ctx@wo + bo + h_f   (residual fused)
        gemm64_kernel<<<dim3(64, 8), 256, 0, stream>>>(
            ctx, wt_l + 3ull * 1024 * 1024, bo + l * 1024, h_f, delta, 4096, 1024, 1024);
        add_ln_kernel<<<dim3(4096), 256, 0, stream>>>(
            delta, g1 + l * 1024, b1 + l * 1024, h_f, h_b);
        // delta = h_b@wf + bf + h_f   (residual fused)
        gemm64_kernel<<<dim3(64, 8), 256, 0, stream>>>(
            h_b, wt_l + 4ull * 1024 * 1024, bfp + l * 1024, h_f, delta, 4096, 1024, 1024);
        float* outf = (l == 3) ? (float*)d_out : h_f;
        add_ln_kernel<<<dim3(4096), 256, 0, stream>>>(
            delta, g2 + l * 1024, b2 + l * 1024, outf, h_b);
    }
    (void)in_sizes; (void)n_in; (void)out_size; (void)ws_size;
}

// Round 4
// 771.823 us; speedup vs baseline: 1.1372x; 1.1372x over previous
//
#include <hip/hip_runtime.h>
#include <hip/hip_bf16.h>
#include <math.h>

typedef __hip_bfloat16 bf16;
typedef unsigned int u32;
typedef __attribute__((ext_vector_type(8))) short short8;   // 8 x bf16 MFMA A/B frag
typedef __attribute__((ext_vector_type(4))) float f32x4;    // MFMA C/D frag

// MFMA 16x16x32 bf16 verified layouts (learn_hip m89/m91):
//   A-frag: A[m = lane&15][k = (lane>>4)*8 + j]
//   B-frag: B[k = (lane>>4)*8 + j][n = lane&15]
//   C/D   : col = lane&15, row = (lane>>4)*4 + reg

#define ATT_LDK 72
#define PS_LD  72     // staging stride: 144B row (16B-aligned for b128)

typedef __attribute__((address_space(3))) u32 lds_u32;
typedef const __attribute__((address_space(1))) u32 glb_u32;
static __device__ __forceinline__ void g2l16(const void* g, void* l) {
    __builtin_amdgcn_global_load_lds((glb_u32*)g, (lds_u32*)l, 16, 0, 0);
}

static __device__ __forceinline__ unsigned short bf16bits(float f) {
    bf16 h = __float2bfloat16(f);
    return *(unsigned short*)&h;
}

// ---------------------------------------------------------------------------
// Weight prep: W fp32 [K=1024, N=1024] -> Wt bf16 [N, K]  (20 matrices)
// ---------------------------------------------------------------------------
__global__ __launch_bounds__(256) void wprep_kernel(
    const float* __restrict__ wq, const float* __restrict__ wk,
    const float* __restrict__ wv, const float* __restrict__ wo,
    const float* __restrict__ wf, bf16* __restrict__ wt_all)
{
    __shared__ bf16 tile[64][ATT_LDK];
    const int z = blockIdx.z;
    const int l = z / 5, f = z % 5;
    const float* src = (f == 0) ? wq : (f == 1) ? wk : (f == 2) ? wv : (f == 3) ? wo : wf;
    src += (size_t)l * 1024 * 1024;
    bf16* dst = wt_all + ((size_t)l * 5 + f) * 1024 * 1024;

    const int k0 = blockIdx.x * 64, n0 = blockIdx.y * 64;
    const int t = threadIdx.x;
#pragma unroll
    for (int rr = 0; rr < 4; ++rr) {
        int slot = t + rr * 256;
        int r = slot >> 4, c = slot & 15;
        float4 v = *(const float4*)(src + (size_t)(k0 + r) * 1024 + n0 + c * 4);
        tile[c * 4 + 0][r] = __float2bfloat16(v.x);
        tile[c * 4 + 1][r] = __float2bfloat16(v.y);
        tile[c * 4 + 2][r] = __float2bfloat16(v.z);
        tile[c * 4 + 3][r] = __float2bfloat16(v.w);
    }
    __syncthreads();
#pragma unroll
    for (int rr = 0; rr < 2; ++rr) {
        int slot = t + rr * 256;
        int n = slot >> 3, c = slot & 7;
        *(uint4*)(dst + (size_t)(n0 + n) * 1024 + k0 + c * 8) = *(const uint4*)&tile[n][c * 8];
    }
}

// stacked qkv bias: bqkv[l][3072] = [bq[l] | bk[l] | bv[l]]
// + PE rate table: rate[d] (1024 entries), hoisted out of pe_kernel where it
//   was recomputed 1M times in f64; bit-identical values.
__global__ void bias_stack_kernel(const float* __restrict__ bq, const float* __restrict__ bk,
                                  const float* __restrict__ bv, float* __restrict__ bqkv,
                                  float* __restrict__ rate)
{
    int i = blockIdx.x * 256 + threadIdx.x;
    if (i < 1024) {
        int m = (i < 512) ? i : (i - 512);
        float ex = (float)(2 * m) * (1.0f / 1024.0f);
        rate[i] = (float)pow(10000.0, (double)ex);
    }
    if (i < 4 * 3072) {
        int l = i / 3072, c = i % 3072;
        int fam = c >> 10, cc = c & 1023;
        const float* s = (fam == 0) ? bq : (fam == 1) ? bk : bv;
        bqkv[i] = s[l * 1024 + cc];
    }
}

// ---------------------------------------------------------------------------
// PE table: pe[s][d]. rate[] precomputed (same bits); f64 sin/cos kept.
// ---------------------------------------------------------------------------
__global__ __launch_bounds__(256) void pe_kernel(const float* __restrict__ rate,
                                                 float* __restrict__ pe)
{
    int idx = blockIdx.x * 256 + threadIdx.x;     // 0 .. 256K-1
    int d0 = (idx & 255) * 4;
    int s = idx >> 8;
    float out[4];
#pragma unroll
    for (int j = 0; j < 4; ++j) {
        int d = d0 + j;
        float ang = (float)s * rate[d];               // f32 rounding matches ref
        double a = (double)ang;
        out[j] = (d < 512) ? (float)sin(a) : (float)cos(a);
    }
    *(float4*)(pe + (size_t)s * 1024 + d0) = *(float4*)out;
}

// ---------------------------------------------------------------------------
// Embedding gather + PE add.
// ---------------------------------------------------------------------------
__global__ __launch_bounds__(256) void embed_kernel(
    const int* __restrict__ x, const float* __restrict__ emb,
    const float* __restrict__ pe,
    float* __restrict__ hf, bf16* __restrict__ hb)
{
    int idx = blockIdx.x * 256 + threadIdx.x;     // 0 .. 1M-1
    int d0 = (idx & 255) * 4;
    int row = idx >> 8;                           // b*1024 + s
    int s = row & 1023;
    int tok = x[row];
    float4 e = *(const float4*)(emb + (size_t)tok * 1024 + d0);
    float4 p = *(const float4*)(pe + (size_t)s * 1024 + d0);
    float out[4] = {e.x * 32.0f + p.x, e.y * 32.0f + p.y,
                    e.z * 32.0f + p.z, e.w * 32.0f + p.w};
    *(float4*)(hf + (size_t)row * 1024 + d0) = *(float4*)out;
    unsigned short pk[4];
#pragma unroll
    for (int j = 0; j < 4; ++j) pk[j] = bf16bits(out[j]);
    *(uint2*)(hb + (size_t)row * 1024 + d0) = *(uint2*)pk;
}

// ---------------------------------------------------------------------------
// GEMM 128x128, BK=32, 4 waves. global_load_lds + XOR slot swizzle.
// Double-buffered; stage k0+32 issued right after the single barrier.
// Epilogues: bf16 via LDS->uint4 (Cb); V-block transposed write into Vt
// (n0>=2048 && VtOut) -- fuses the old transpose_v kernel into the QKV GEMM.
// ---------------------------------------------------------------------------
__global__ __launch_bounds__(256, 3) void gemm_bt_kernel(
    const bf16* __restrict__ A, const bf16* __restrict__ Bt,
    const float* __restrict__ bias,
    bf16* __restrict__ Cb, bf16* __restrict__ VtOut,
    int M, int N, int K)
{
    __shared__ bf16 As[2][128 * 32];
    __shared__ bf16 Bs[2][128 * 32];
    __shared__ bf16 Cst[4][16 * PS_LD];
    const int t = threadIdx.x;
    const int lane = t & 63, wave = t >> 6;
    const int wr = wave >> 1, wc = wave & 1;
    const int lidx = lane & 15, quad = lane >> 4;
    const int m0 = blockIdx.x * 128, n0 = blockIdx.y * 128;

    f32x4 acc[4][4];
#pragma unroll
    for (int i = 0; i < 4; ++i)
#pragma unroll
        for (int j = 0; j < 4; ++j) acc[i][j] = (f32x4){0.f, 0.f, 0.f, 0.f};

    const int r0 = wave * 32;
    const int rloc = lane >> 2;
    const int csw = ((lane & 3) ^ ((lane >> 3) & 3)) * 8;
    const bf16* Abase = A  + (size_t)(m0 + r0 + rloc) * K + csw;
    const bf16* Bbase = Bt + (size_t)(n0 + r0 + rloc) * K + csw;
    const int lofs = r0 * 32;
    const int aslot = (quad ^ ((lidx >> 1) & 3)) * 8;

    g2l16(Abase,                  &As[0][lofs]);
    g2l16(Abase + 16 * (size_t)K, &As[0][lofs + 16 * 32]);
    g2l16(Bbase,                  &Bs[0][lofs]);
    g2l16(Bbase + 16 * (size_t)K, &Bs[0][lofs + 16 * 32]);

    for (int k0 = 0; k0 < K; k0 += 32) {
        __syncthreads();
        const int cur = (k0 >> 5) & 1;
        if (k0 + 32 < K) {
            const int kn = k0 + 32;
            g2l16(Abase + kn,                  &As[cur ^ 1][lofs]);
            g2l16(Abase + kn + 16 * (size_t)K, &As[cur ^ 1][lofs + 16 * 32]);
            g2l16(Bbase + kn,                  &Bs[cur ^ 1][lofs]);
            g2l16(Bbase + kn + 16 * (size_t)K, &Bs[cur ^ 1][lofs + 16 * 32]);
        }

        short8 af[4], bfr[4];
#pragma unroll
        for (int i = 0; i < 4; ++i)
            af[i] = *(const short8*)(&As[cur][(wr * 64 + i * 16 + lidx) * 32 + aslot]);
#pragma unroll
        for (int j = 0; j < 4; ++j)
            bfr[j] = *(const short8*)(&Bs[cur][(wc * 64 + j * 16 + lidx) * 32 + aslot]);
#pragma unroll
        for (int i = 0; i < 4; ++i)
#pragma unroll
            for (int j = 0; j < 4; ++j)
                acc[i][j] = __builtin_amdgcn_mfma_f32_16x16x32_bf16(af[i], bfr[j], acc[i][j], 0, 0, 0);
    }

    float bvj[4];
#pragma unroll
    for (int j = 0; j < 4; ++j)
        bvj[j] = bias ? bias[n0 + wc * 64 + j * 16 + lidx] : 0.0f;

    if (VtOut && n0 >= 2048) {
        const int bidx = m0 >> 10;
        const int s_base = (m0 & 1023) + wr * 64 + quad * 4;
        const int d_base = (n0 - 2048) + wc * 64;
#pragma unroll
        for (int i = 0; i < 4; ++i)
#pragma unroll
            for (int j = 0; j < 4; ++j) {
                unsigned short pk[4];
#pragma unroll
                for (int r = 0; r < 4; ++r)
                    pk[r] = bf16bits(acc[i][j][r] + bvj[j]);
                bf16* dst = VtOut + ((size_t)bidx * 1024 + d_base + j * 16 + lidx) * 1024
                            + s_base + i * 16;
                *(uint2*)dst = *(const uint2*)pk;
            }
    } else {
        const int row16 = lane >> 2, c4 = lane & 3;
#pragma unroll
        for (int i = 0; i < 4; ++i) {
#pragma unroll
            for (int j = 0; j < 4; ++j)
#pragma unroll
                for (int r = 0; r < 4; ++r)
                    Cst[wave][(quad * 4 + r) * PS_LD + j * 16 + lidx] =
                        __float2bfloat16(acc[i][j][r] + bvj[j]);
            bf16* dst = Cb + (size_t)(m0 + wr * 64 + i * 16 + row16) * N + n0 + wc * 64;
            const bf16* srcr = &Cst[wave][row16 * PS_LD];
#pragma unroll
            for (int h = 0; h < 2; ++h)
                *(uint4*)(dst + (c4 + 4 * h) * 8) = *(const uint4*)(srcr + (c4 + 4 * h) * 8);
        }
    }
}

// ---------------------------------------------------------------------------
// GEMM 64x128 tile (fp32 out) for N=1024 projections.
// Double-buffered staging + fused residual add: Cf = A@Bt + bias + resid.
// ---------------------------------------------------------------------------
__global__ __launch_bounds__(256, 4) void gemm64_kernel(
    const bf16* __restrict__ A, const bf16* __restrict__ Bt,
    const float* __restrict__ bias, const float* __restrict__ resid,
    float* __restrict__ Cf,
    int M, int N, int K)
{
    __shared__ bf16 As[2][64 * 32];
    __shared__ bf16 Bs[2][128 * 32];
    const int t = threadIdx.x;
    const int lane = t & 63, wave = t >> 6;
    const int wr = wave >> 1, wc = wave & 1;
    const int lidx = lane & 15, quad = lane >> 4;
    const int m0 = blockIdx.x * 64, n0 = blockIdx.y * 128;

    f32x4 acc[2][4];
#pragma unroll
    for (int i = 0; i < 2; ++i)
#pragma unroll
        for (int j = 0; j < 4; ++j) acc[i][j] = (f32x4){0.f, 0.f, 0.f, 0.f};

    const int rloc = lane >> 2;
    const int csw = ((lane & 3) ^ ((lane >> 3) & 3)) * 8;
    const bf16* Abase = A  + (size_t)(m0 + wave * 16 + rloc) * K + csw;
    const bf16* Bbase = Bt + (size_t)(n0 + wave * 32 + rloc) * K + csw;
    const int alofs = wave * 16 * 32;
    const int blofs = wave * 32 * 32;
    const int aslot = (quad ^ ((lidx >> 1) & 3)) * 8;

    g2l16(Abase,                  &As[0][alofs]);
    g2l16(Bbase,                  &Bs[0][blofs]);
    g2l16(Bbase + 16 * (size_t)K, &Bs[0][blofs + 16 * 32]);

    for (int k0 = 0; k0 < K; k0 += 32) {
        __syncthreads();
        const int cur = (k0 >> 5) & 1;
        if (k0 + 32 < K) {
            const int kn = k0 + 32;
            g2l16(Abase + kn,                  &As[cur ^ 1][alofs]);
            g2l16(Bbase + kn,                  &Bs[cur ^ 1][blofs]);
            g2l16(Bbase + kn + 16 * (size_t)K, &Bs[cur ^ 1][blofs + 16 * 32]);
        }

        short8 af[2], bfr[4];
#pragma unroll
        for (int i = 0; i < 2; ++i)
            af[i] = *(const short8*)(&As[cur][(wr * 32 + i * 16 + lidx) * 32 + aslot]);
#pragma unroll
        for (int j = 0; j < 4; ++j)
            bfr[j] = *(const short8*)(&Bs[cur][(wc * 64 + j * 16 + lidx) * 32 + aslot]);
#pragma unroll
        for (int i = 0; i < 2; ++i)
#pragma unroll
            for (int j = 0; j < 4; ++j)
                acc[i][j] = __builtin_amdgcn_mfma_f32_16x16x32_bf16(af[i], bfr[j], acc[i][j], 0, 0, 0);
    }

#pragma unroll
    for (int i = 0; i < 2; ++i)
#pragma unroll
        for (int j = 0; j < 4; ++j) {
            int col = n0 + wc * 64 + j * 16 + lidx;
            float bv = bias[col];
#pragma unroll
            for (int r = 0; r < 4; ++r) {
                int rowg = m0 + wr * 32 + i * 16 + quad * 4 + r;
                Cf[(size_t)rowg * N + col] =
                    acc[i][j][r] + bv + resid[(size_t)rowg * N + col];
            }
        }
}

// ---------------------------------------------------------------------------
// Flash attention, no-max softmax. Per block: (b,h) x 128 q-rows, 8 waves.
// grid(64,8): all q-tiles of one (b,h) land on one XCD.
// RESTORED to the R1 known-good structure: Ks+Vs double-buffered DMA staging
// (the staging IS the latency-hiding mechanism; V-direct-from-L2 regressed
// +100us by exposing ~300cy per tile inside the PV loop), global mask reads
// (keeps LDS at 50KB -> 3 blocks/CU; the 4KB Ms table dropped occupancy).
// ---------------------------------------------------------------------------
__global__ __launch_bounds__(512, 4) void attention_kernel(
    const bf16* __restrict__ QKV,    // [4096, 3072] = [q|k|-]
    const bf16* __restrict__ Vt,     // [b][d(1024)][s(1024)]
    const float* __restrict__ mask,  // [4,1024]
    bf16* __restrict__ ctx)          // [4096, 1024]
{
    __shared__ bf16 Ks[2][64 * 64];
    __shared__ bf16 Vs[2][64 * 64];
    __shared__ bf16 Ps[8][16 * PS_LD];

    const int t = threadIdx.x, lane = t & 63, wave = t >> 6;
    const int quad = lane >> 4, lidx = lane & 15;
    const int b = blockIdx.x >> 4, hh = blockIdx.x & 15;
    const int q0 = blockIdx.y * 128 + wave * 16;

    const int r8 = lane >> 3;
    const int gc = ((lane & 7) ^ r8) * 8;
    const bf16* kg0 = QKV + (size_t)(b * 1024 + wave * 8 + r8) * 3072 + 1024 + hh * 64 + gc;
    const bf16* vg0 = Vt  + (size_t)(b * 1024 + hh * 64 + wave * 8 + r8) * 1024 + gc;
    const int lofs = wave * 8 * 64;

    short8 qf[2];
    {
        const bf16* qp = QKV + (size_t)(b * 1024 + q0 + lidx) * 3072 + hh * 64;
        qf[0] = *(const short8*)(qp + quad * 8);
        qf[1] = *(const short8*)(qp + 32 + quad * 8);
    }

    f32x4 Oacc[4];
#pragma unroll
    for (int nt = 0; nt < 4; ++nt) Oacc[nt] = (f32x4){0.f, 0.f, 0.f, 0.f};
    float psum[4] = {0.f, 0.f, 0.f, 0.f};

    const int fslot = lidx & 7;

    g2l16(kg0, &Ks[0][lofs]);
    g2l16(vg0, &Vs[0][lofs]);

    for (int kt = 0; kt < 16; ++kt) {
        __syncthreads();
        const int cur = kt & 1;
        if (kt < 15) {
            g2l16(kg0 + (size_t)(kt + 1) * 64 * 3072, &Ks[cur ^ 1][lofs]);
            g2l16(vg0 + (kt + 1) * 64,                &Vs[cur ^ 1][lofs]);
        }

        f32x4 sacc[4];
#pragma unroll
        for (int nt = 0; nt < 4; ++nt) sacc[nt] = (f32x4){0.f, 0.f, 0.f, 0.f};
#pragma unroll
        for (int kk = 0; kk < 2; ++kk)
#pragma unroll
            for (int nt = 0; nt < 4; ++nt) {
                short8 kf = *(const short8*)(&Ks[cur][(nt * 16 + lidx) * 64 + (((kk * 4 + quad) ^ fslot) * 8)]);
                sacc[nt] = __builtin_amdgcn_mfma_f32_16x16x32_bf16(qf[kk], kf, sacc[nt], 0, 0, 0);
            }

#pragma unroll
        for (int nt = 0; nt < 4; ++nt) {
            float mv = mask[b * 1024 + kt * 64 + nt * 16 + lidx] * -1e9f;
#pragma unroll
            for (int r = 0; r < 4; ++r) {
                float p = __expf(sacc[nt][r] * 0.125f + mv);
                sacc[nt][r] = p;
                psum[r] += p;
            }
        }

#pragma unroll
        for (int nt = 0; nt < 4; ++nt)
#pragma unroll
            for (int r = 0; r < 4; ++r)
                Ps[wave][(quad * 4 + r) * PS_LD + nt * 16 + lidx] = __float2bfloat16(sacc[nt][r]);

#pragma unroll
        for (int kk = 0; kk < 2; ++kk) {
            short8 pf = *(const short8*)(&Ps[wave][lidx * PS_LD + kk * 32 + quad * 8]);
#pragma unroll
            for (int nt = 0; nt < 4; ++nt) {
                short8 vf = *(const short8*)(&Vs[cur][(nt * 16 + lidx) * 64 + (((kk * 4 + quad) ^ fslot) * 8)]);
                Oacc[nt] = __builtin_amdgcn_mfma_f32_16x16x32_bf16(pf, vf, Oacc[nt], 0, 0, 0);
            }
        }
    }

#pragma unroll
    for (int off = 1; off < 16; off <<= 1)
#pragma unroll
        for (int r = 0; r < 4; ++r)
            psum[r] += __shfl_xor(psum[r], off, 64);
    float linv[4];
#pragma unroll
    for (int r = 0; r < 4; ++r) linv[r] = 1.0f / psum[r];

#pragma unroll
    for (int nt = 0; nt < 4; ++nt)
#pragma unroll
        for (int r = 0; r < 4; ++r)
            Ps[wave][(quad * 4 + r) * PS_LD + nt * 16 + lidx] = __float2bfloat16(Oacc[nt][r] * linv[r]);

    const int row16 = lane >> 2, c4 = lane & 3;
    bf16* dst = ctx + (size_t)(b * 1024 + q0 + row16) * 1024 + hh * 64;
    const bf16* srcr = &Ps[wave][row16 * PS_LD];
#pragma unroll
    for (int h = 0; h < 2; ++h)
        *(uint4*)(dst + (c4 + 4 * h) * 8) = *(const uint4*)(srcr + (c4 + 4 * h) * 8);
}

// ---------------------------------------------------------------------------
// h = LN(x) * g + b.  x already contains residual+delta (fused in gemm64).
// ---------------------------------------------------------------------------
__global__ __launch_bounds__(256) void add_ln_kernel(
    const float* __restrict__ x,
    const float* __restrict__ g, const float* __restrict__ b,
    float* __restrict__ outf, bf16* __restrict__ outb)
{
    __shared__ float red[4];
    const int row = blockIdx.x;
    const int t = threadIdx.x;
    const int c0 = t * 4;
    float4 xv = *(const float4*)(x + (size_t)row * 1024 + c0);
    float v[4] = {xv.x, xv.y, xv.z, xv.w};
    float s = v[0] + v[1] + v[2] + v[3];
#pragma unroll
    for (int off = 1; off < 64; off <<= 1) s += __shfl_xor(s, off, 64);
    if ((t & 63) == 0) red[t >> 6] = s;
    __syncthreads();
    float mean = (red[0] + red[1] + red[2] + red[3]) * (1.0f / 1024.0f);
    float sq = 0.f;
#pragma unroll
    for (int i = 0; i < 4; ++i) { float d = v[i] - mean; sq += d * d; }
#pragma unroll
    for (int off = 1; off < 64; off <<= 1) sq += __shfl_xor(sq, off, 64);
    __syncthreads();
    if ((t & 63) == 0) red[t >> 6] = sq;
    __syncthreads();
    float var = (red[0] + red[1] + red[2] + red[3]) * (1.0f / 1024.0f);
    float rs = rsqrtf(var + 1e-6f);
    float4 gv = *(const float4*)(g + c0);
    float4 bv = *(const float4*)(b + c0);
    float gg[4] = {gv.x, gv.y, gv.z, gv.w}, bb[4] = {bv.x, bv.y, bv.z, bv.w};
    float o[4];
    unsigned short pk[4];
#pragma unroll
    for (int i = 0; i < 4; ++i) {
        o[i] = (v[i] - mean) * rs * gg[i] + bb[i];
        pk[i] = bf16bits(o[i]);
    }
    *(float4*)(outf + (size_t)row * 1024 + c0) = *(float4*)o;
    *(uint2*)(outb + (size_t)row * 1024 + c0) = *(uint2*)pk;
}

// ---------------------------------------------------------------------------
extern "C" void kernel_launch(void* const* d_in, const int* in_sizes, int n_in,
                              void* d_out, int out_size, void* d_ws, size_t ws_size,
                              hipStream_t stream)
{
    const int*   x    = (const int*)d_in[0];
    const float* mask = (const float*)d_in[1];
    const float* emb  = (const float*)d_in[2];
    const float* wq   = (const float*)d_in[3];
    const float* bq   = (const float*)d_in[4];
    const float* wk   = (const float*)d_in[5];
    const float* bk   = (const float*)d_in[6];
    const float* wv   = (const float*)d_in[7];
    const float* bv   = (const float*)d_in[8];
    const float* wo   = (const float*)d_in[9];
    const float* bo   = (const float*)d_in[10];
    const float* wf   = (const float*)d_in[11];
    const float* bfp  = (const float*)d_in[12];
    const float* g1   = (const float*)d_in[13];
    const float* b1   = (const float*)d_in[14];
    const float* g2   = (const float*)d_in[15];
    const float* b2   = (const float*)d_in[16];

    char* ws = (char*)d_ws;
    float* h_f  = (float*)ws;                 ws += 4096ull * 1024 * 4;   // 16 MB
    bf16*  h_b  = (bf16*)ws;                  ws += 4096ull * 1024 * 2;   //  8 MB
    bf16*  qkv  = (bf16*)ws;                  ws += 4096ull * 3072 * 2;   // 24 MB
    bf16*  vt   = (bf16*)ws;                  ws += 4096ull * 1024 * 2;   //  8 MB
    bf16*  ctx  = (bf16*)ws;                  ws += 4096ull * 1024 * 2;   //  8 MB
    bf16*  wt   = (bf16*)ws;                  ws += 20ull * 1024 * 1024 * 2; // 40 MB
    float* pe   = (float*)ws;                 ws += 1024ull * 1024 * 4;   //  4 MB
    float* bqkv = (float*)ws;                 ws += 4ull * 3072 * 4;
    float* rate = (float*)ws;                 ws += 1024ull * 4;
    float* delta = (float*)qkv;  // fp32 GEMM out, alias of qkv (dead by then)

    wprep_kernel<<<dim3(16, 16, 20), 256, 0, stream>>>(wq, wk, wv, wo, wf, wt);
    bias_stack_kernel<<<dim3(48), 256, 0, stream>>>(bq, bk, bv, bqkv, rate);
    pe_kernel<<<dim3(1024), 256, 0, stream>>>(rate, pe);
    embed_kernel<<<dim3(4096), 256, 0, stream>>>(x, emb, pe, h_f, h_b);

    for (int l = 0; l < 4; ++l) {
        bf16* wt_l = wt + (size_t)l * 5 * 1024 * 1024;
        // QKV: Q,K -> qkv cols [0,2048); V -> vt transposed (fused)
        gemm_bt_kernel<<<dim3(32, 24), 256, 0, stream>>>(
            h_b, wt_l, bqkv + l * 3072, qkv, vt, 4096, 3072, 1024);
        attention_kernel<<<dim3(64, 8), 512, 0, stream>>>(qkv, vt, mask, ctx);
        // delta = ctx@wo + bo + h_f   (residual fused)
        gemm64_kernel<<<dim3(64, 8), 256, 0, stream>>>(
            ctx, wt_l + 3ull * 1024 * 1024, bo + l * 1024, h_f, delta, 4096, 1024, 1024);
        add_ln_kernel<<<dim3(4096), 256, 0, stream>>>(
            delta, g1 + l * 1024, b1 + l * 1024, h_f, h_b);
        // delta = h_b@wf + bf + h_f   (residual fused)
        gemm64_kernel<<<dim3(64, 8), 256, 0, stream>>>(
            h_b, wt_l + 4ull * 1024 * 1024, bfp + l * 1024, h_f, delta, 4096, 1024, 1024);
        float* outf = (l == 3) ? (float*)d_out : h_f;
        add_ln_kernel<<<dim3(4096), 256, 0, stream>>>(
            delta, g2 + l * 1024, b2 + l * 1024, outf, h_b);
    }
    (void)in_sizes; (void)n_in; (void)out_size; (void)ws_size;
}

// Round 5
// 760.588 us; speedup vs baseline: 1.1540x; 1.0148x over previous
//
#include <hip/hip_runtime.h>
#include <hip/hip_bf16.h>
#include <math.h>

typedef __hip_bfloat16 bf16;
typedef unsigned int u32;
typedef __attribute__((ext_vector_type(8))) short short8;   // 8 x bf16 MFMA A/B frag
typedef __attribute__((ext_vector_type(4))) float f32x4;    // MFMA C/D frag

// MFMA 16x16x32 bf16 verified layouts (learn_hip m89/m91):
//   A-frag: A[m = lane&15][k = (lane>>4)*8 + j]
//   B-frag: B[k = (lane>>4)*8 + j][n = lane&15]
//   C/D   : col = lane&15, row = (lane>>4)*4 + reg

#define ATT_LDK 72
#define PS_LD  72     // staging stride: 144B row (16B-aligned for b128)

typedef __attribute__((address_space(3))) u32 lds_u32;
typedef const __attribute__((address_space(1))) u32 glb_u32;
static __device__ __forceinline__ void g2l16(const void* g, void* l) {
    __builtin_amdgcn_global_load_lds((glb_u32*)g, (lds_u32*)l, 16, 0, 0);
}

static __device__ __forceinline__ unsigned short bf16bits(float f) {
    bf16 h = __float2bfloat16(f);
    return *(unsigned short*)&h;
}

// ---------------------------------------------------------------------------
// Weight prep: W fp32 [K=1024, N=1024] -> Wt bf16 [N, K]  (20 matrices)
// ---------------------------------------------------------------------------
__global__ __launch_bounds__(256) void wprep_kernel(
    const float* __restrict__ wq, const float* __restrict__ wk,
    const float* __restrict__ wv, const float* __restrict__ wo,
    const float* __restrict__ wf, bf16* __restrict__ wt_all)
{
    __shared__ bf16 tile[64][ATT_LDK];
    const int z = blockIdx.z;
    const int l = z / 5, f = z % 5;
    const float* src = (f == 0) ? wq : (f == 1) ? wk : (f == 2) ? wv : (f == 3) ? wo : wf;
    src += (size_t)l * 1024 * 1024;
    bf16* dst = wt_all + ((size_t)l * 5 + f) * 1024 * 1024;

    const int k0 = blockIdx.x * 64, n0 = blockIdx.y * 64;
    const int t = threadIdx.x;
#pragma unroll
    for (int rr = 0; rr < 4; ++rr) {
        int slot = t + rr * 256;
        int r = slot >> 4, c = slot & 15;
        float4 v = *(const float4*)(src + (size_t)(k0 + r) * 1024 + n0 + c * 4);
        tile[c * 4 + 0][r] = __float2bfloat16(v.x);
        tile[c * 4 + 1][r] = __float2bfloat16(v.y);
        tile[c * 4 + 2][r] = __float2bfloat16(v.z);
        tile[c * 4 + 3][r] = __float2bfloat16(v.w);
    }
    __syncthreads();
#pragma unroll
    for (int rr = 0; rr < 2; ++rr) {
        int slot = t + rr * 256;
        int n = slot >> 3, c = slot & 7;
        *(uint4*)(dst + (size_t)(n0 + n) * 1024 + k0 + c * 8) = *(const uint4*)&tile[n][c * 8];
    }
}

// stacked qkv bias: bqkv[l][3072] = [bq[l] | bk[l] | bv[l]]
// + PE rate table: rate[d] (1024 entries), hoisted out of pe_kernel.
__global__ void bias_stack_kernel(const float* __restrict__ bq, const float* __restrict__ bk,
                                  const float* __restrict__ bv, float* __restrict__ bqkv,
                                  float* __restrict__ rate)
{
    int i = blockIdx.x * 256 + threadIdx.x;
    if (i < 1024) {
        int m = (i < 512) ? i : (i - 512);
        float ex = (float)(2 * m) * (1.0f / 1024.0f);
        rate[i] = (float)pow(10000.0, (double)ex);
    }
    if (i < 4 * 3072) {
        int l = i / 3072, c = i % 3072;
        int fam = c >> 10, cc = c & 1023;
        const float* s = (fam == 0) ? bq : (fam == 1) ? bk : bv;
        bqkv[i] = s[l * 1024 + cc];
    }
}

// ---------------------------------------------------------------------------
// PE table: pe[s][d]. rate[] precomputed (same bits); f64 sin/cos kept.
// ---------------------------------------------------------------------------
__global__ __launch_bounds__(256) void pe_kernel(const float* __restrict__ rate,
                                                 float* __restrict__ pe)
{
    int idx = blockIdx.x * 256 + threadIdx.x;     // 0 .. 256K-1
    int d0 = (idx & 255) * 4;
    int s = idx >> 8;
    float out[4];
#pragma unroll
    for (int j = 0; j < 4; ++j) {
        int d = d0 + j;
        float ang = (float)s * rate[d];               // f32 rounding matches ref
        double a = (double)ang;
        out[j] = (d < 512) ? (float)sin(a) : (float)cos(a);
    }
    *(float4*)(pe + (size_t)s * 1024 + d0) = *(float4*)out;
}

// ---------------------------------------------------------------------------
// Embedding gather + PE add.
// ---------------------------------------------------------------------------
__global__ __launch_bounds__(256) void embed_kernel(
    const int* __restrict__ x, const float* __restrict__ emb,
    const float* __restrict__ pe,
    float* __restrict__ hf, bf16* __restrict__ hb)
{
    int idx = blockIdx.x * 256 + threadIdx.x;     // 0 .. 1M-1
    int d0 = (idx & 255) * 4;
    int row = idx >> 8;                           // b*1024 + s
    int s = row & 1023;
    int tok = x[row];
    float4 e = *(const float4*)(emb + (size_t)tok * 1024 + d0);
    float4 p = *(const float4*)(pe + (size_t)s * 1024 + d0);
    float out[4] = {e.x * 32.0f + p.x, e.y * 32.0f + p.y,
                    e.z * 32.0f + p.z, e.w * 32.0f + p.w};
    *(float4*)(hf + (size_t)row * 1024 + d0) = *(float4*)out;
    unsigned short pk[4];
#pragma unroll
    for (int j = 0; j < 4; ++j) pk[j] = bf16bits(out[j]);
    *(uint2*)(hb + (size_t)row * 1024 + d0) = *(uint2*)pk;
}

// ---------------------------------------------------------------------------
// GEMM 128x128, BK=32, 4 waves. global_load_lds + XOR slot swizzle.
// Double-buffered; stage k0+32 issued right after the single barrier.
// Epilogues: bf16 via LDS->uint4 (Cb); V-block transposed write into Vt
// (n0>=2048 && VtOut) -- fuses the old transpose_v kernel into the QKV GEMM.
// ---------------------------------------------------------------------------
__global__ __launch_bounds__(256, 3) void gemm_bt_kernel(
    const bf16* __restrict__ A, const bf16* __restrict__ Bt,
    const float* __restrict__ bias,
    bf16* __restrict__ Cb, bf16* __restrict__ VtOut,
    int M, int N, int K)
{
    __shared__ bf16 As[2][128 * 32];
    __shared__ bf16 Bs[2][128 * 32];
    __shared__ bf16 Cst[4][16 * PS_LD];
    const int t = threadIdx.x;
    const int lane = t & 63, wave = t >> 6;
    const int wr = wave >> 1, wc = wave & 1;
    const int lidx = lane & 15, quad = lane >> 4;
    const int m0 = blockIdx.x * 128, n0 = blockIdx.y * 128;

    f32x4 acc[4][4];
#pragma unroll
    for (int i = 0; i < 4; ++i)
#pragma unroll
        for (int j = 0; j < 4; ++j) acc[i][j] = (f32x4){0.f, 0.f, 0.f, 0.f};

    const int r0 = wave * 32;
    const int rloc = lane >> 2;
    const int csw = ((lane & 3) ^ ((lane >> 3) & 3)) * 8;
    const bf16* Abase = A  + (size_t)(m0 + r0 + rloc) * K + csw;
    const bf16* Bbase = Bt + (size_t)(n0 + r0 + rloc) * K + csw;
    const int lofs = r0 * 32;
    const int aslot = (quad ^ ((lidx >> 1) & 3)) * 8;

    g2l16(Abase,                  &As[0][lofs]);
    g2l16(Abase + 16 * (size_t)K, &As[0][lofs + 16 * 32]);
    g2l16(Bbase,                  &Bs[0][lofs]);
    g2l16(Bbase + 16 * (size_t)K, &Bs[0][lofs + 16 * 32]);

    for (int k0 = 0; k0 < K; k0 += 32) {
        __syncthreads();
        const int cur = (k0 >> 5) & 1;
        if (k0 + 32 < K) {
            const int kn = k0 + 32;
            g2l16(Abase + kn,                  &As[cur ^ 1][lofs]);
            g2l16(Abase + kn + 16 * (size_t)K, &As[cur ^ 1][lofs + 16 * 32]);
            g2l16(Bbase + kn,                  &Bs[cur ^ 1][lofs]);
            g2l16(Bbase + kn + 16 * (size_t)K, &Bs[cur ^ 1][lofs + 16 * 32]);
        }

        short8 af[4], bfr[4];
#pragma unroll
        for (int i = 0; i < 4; ++i)
            af[i] = *(const short8*)(&As[cur][(wr * 64 + i * 16 + lidx) * 32 + aslot]);
#pragma unroll
        for (int j = 0; j < 4; ++j)
            bfr[j] = *(const short8*)(&Bs[cur][(wc * 64 + j * 16 + lidx) * 32 + aslot]);
#pragma unroll
        for (int i = 0; i < 4; ++i)
#pragma unroll
            for (int j = 0; j < 4; ++j)
                acc[i][j] = __builtin_amdgcn_mfma_f32_16x16x32_bf16(af[i], bfr[j], acc[i][j], 0, 0, 0);
    }

    float bvj[4];
#pragma unroll
    for (int j = 0; j < 4; ++j)
        bvj[j] = bias ? bias[n0 + wc * 64 + j * 16 + lidx] : 0.0f;

    if (VtOut && n0 >= 2048) {
        const int bidx = m0 >> 10;
        const int s_base = (m0 & 1023) + wr * 64 + quad * 4;
        const int d_base = (n0 - 2048) + wc * 64;
#pragma unroll
        for (int i = 0; i < 4; ++i)
#pragma unroll
            for (int j = 0; j < 4; ++j) {
                unsigned short pk[4];
#pragma unroll
                for (int r = 0; r < 4; ++r)
                    pk[r] = bf16bits(acc[i][j][r] + bvj[j]);
                bf16* dst = VtOut + ((size_t)bidx * 1024 + d_base + j * 16 + lidx) * 1024
                            + s_base + i * 16;
                *(uint2*)dst = *(const uint2*)pk;
            }
    } else {
        const int row16 = lane >> 2, c4 = lane & 3;
#pragma unroll
        for (int i = 0; i < 4; ++i) {
#pragma unroll
            for (int j = 0; j < 4; ++j)
#pragma unroll
                for (int r = 0; r < 4; ++r)
                    Cst[wave][(quad * 4 + r) * PS_LD + j * 16 + lidx] =
                        __float2bfloat16(acc[i][j][r] + bvj[j]);
            bf16* dst = Cb + (size_t)(m0 + wr * 64 + i * 16 + row16) * N + n0 + wc * 64;
            const bf16* srcr = &Cst[wave][row16 * PS_LD];
#pragma unroll
            for (int h = 0; h < 2; ++h)
                *(uint4*)(dst + (c4 + 4 * h) * 8) = *(const uint4*)(srcr + (c4 + 4 * h) * 8);
        }
    }
}

// ---------------------------------------------------------------------------
// GEMM 64x128 tile (fp32 out) for N=1024 projections.
// Double-buffered staging + fused residual add: Cf = A@Bt + bias + resid.
// ---------------------------------------------------------------------------
__global__ __launch_bounds__(256, 4) void gemm64_kernel(
    const bf16* __restrict__ A, const bf16* __restrict__ Bt,
    const float* __restrict__ bias, const float* __restrict__ resid,
    float* __restrict__ Cf,
    int M, int N, int K)
{
    __shared__ bf16 As[2][64 * 32];
    __shared__ bf16 Bs[2][128 * 32];
    const int t = threadIdx.x;
    const int lane = t & 63, wave = t >> 6;
    const int wr = wave >> 1, wc = wave & 1;
    const int lidx = lane & 15, quad = lane >> 4;
    const int m0 = blockIdx.x * 64, n0 = blockIdx.y * 128;

    f32x4 acc[2][4];
#pragma unroll
    for (int i = 0; i < 2; ++i)
#pragma unroll
        for (int j = 0; j < 4; ++j) acc[i][j] = (f32x4){0.f, 0.f, 0.f, 0.f};

    const int rloc = lane >> 2;
    const int csw = ((lane & 3) ^ ((lane >> 3) & 3)) * 8;
    const bf16* Abase = A  + (size_t)(m0 + wave * 16 + rloc) * K + csw;
    const bf16* Bbase = Bt + (size_t)(n0 + wave * 32 + rloc) * K + csw;
    const int alofs = wave * 16 * 32;
    const int blofs = wave * 32 * 32;
    const int aslot = (quad ^ ((lidx >> 1) & 3)) * 8;

    g2l16(Abase,                  &As[0][alofs]);
    g2l16(Bbase,                  &Bs[0][blofs]);
    g2l16(Bbase + 16 * (size_t)K, &Bs[0][blofs + 16 * 32]);

    for (int k0 = 0; k0 < K; k0 += 32) {
        __syncthreads();
        const int cur = (k0 >> 5) & 1;
        if (k0 + 32 < K) {
            const int kn = k0 + 32;
            g2l16(Abase + kn,                  &As[cur ^ 1][alofs]);
            g2l16(Bbase + kn,                  &Bs[cur ^ 1][blofs]);
            g2l16(Bbase + kn + 16 * (size_t)K, &Bs[cur ^ 1][blofs + 16 * 32]);
        }

        short8 af[2], bfr[4];
#pragma unroll
        for (int i = 0; i < 2; ++i)
            af[i] = *(const short8*)(&As[cur][(wr * 32 + i * 16 + lidx) * 32 + aslot]);
#pragma unroll
        for (int j = 0; j < 4; ++j)
            bfr[j] = *(const short8*)(&Bs[cur][(wc * 64 + j * 16 + lidx) * 32 + aslot]);
#pragma unroll
        for (int i = 0; i < 2; ++i)
#pragma unroll
            for (int j = 0; j < 4; ++j)
                acc[i][j] = __builtin_amdgcn_mfma_f32_16x16x32_bf16(af[i], bfr[j], acc[i][j], 0, 0, 0);
    }

#pragma unroll
    for (int i = 0; i < 2; ++i)
#pragma unroll
        for (int j = 0; j < 4; ++j) {
            int col = n0 + wc * 64 + j * 16 + lidx;
            float bv = bias[col];
#pragma unroll
            for (int r = 0; r < 4; ++r) {
                int rowg = m0 + wr * 32 + i * 16 + quad * 4 + r;
                Cf[(size_t)rowg * N + col] =
                    acc[i][j][r] + bv + resid[(size_t)rowg * N + col];
            }
        }
}

// ---------------------------------------------------------------------------
// Flash attention, no-max softmax. NEW blocking this round:
// 4 waves x 32 q-rows (2 q-subtiles) per block, same 128 q-rows/block,
// grid (64,8) unchanged. Each kf/vf LDS fragment now feeds TWO MFMAs
// -> K/V fragment read traffic HALVES (attention is LDS-BW-bound:
// ~15us/layer of ds_read_b128 at the old 8x amplification).
// Per-q-row arithmetic order identical -> bit-identical output.
// Mask premultiplied to bf16 LDS (2KB; exact for 0/1 masks).
// LDS 52KB; launch_bounds(256,2) -> 2 blocks/CU (grid is 2/CU).
// ---------------------------------------------------------------------------
__global__ __launch_bounds__(256, 2) void attention_kernel(
    const bf16* __restrict__ QKV,    // [4096, 3072] = [q|k|-]
    const bf16* __restrict__ Vt,     // [b][d(1024)][s(1024)]
    const float* __restrict__ mask,  // [4,1024]
    bf16* __restrict__ ctx)          // [4096, 1024]
{
    __shared__ bf16 Ks[2][64 * 64];
    __shared__ bf16 Vs[2][64 * 64];
    __shared__ bf16 Ps[4][32 * PS_LD];
    __shared__ bf16 Ms[1024];

    const int t = threadIdx.x, lane = t & 63, wave = t >> 6;   // 4 waves
    const int quad = lane >> 4, lidx = lane & 15;
    const int b = blockIdx.x >> 4, hh = blockIdx.x & 15;
    const int q0 = blockIdx.y * 128 + wave * 32;               // 32 q-rows/wave

    // staging: each wave loads 16 rows (two 8-row g2l16 per operand)
    const int r8 = lane >> 3;
    const int gc = ((lane & 7) ^ r8) * 8;
    const bf16* kg0 = QKV + (size_t)(b * 1024 + wave * 16 + r8) * 3072 + 1024 + hh * 64 + gc;
    const bf16* vg0 = Vt  + (size_t)(b * 1024 + hh * 64 + wave * 16 + r8) * 1024 + gc;
    const int lofs = wave * 16 * 64;

    // mask -> LDS, premultiplied, bf16 (exact for 0/1 masks; first use after sync)
#pragma unroll
    for (int i = 0; i < 4; ++i)
        Ms[t + i * 256] = __float2bfloat16(mask[b * 1024 + t + i * 256] * -1e9f);

    short8 qf[2][2];   // [qsub][kk]
#pragma unroll
    for (int qs = 0; qs < 2; ++qs) {
        const bf16* qp = QKV + (size_t)(b * 1024 + q0 + qs * 16 + lidx) * 3072 + hh * 64;
        qf[qs][0] = *(const short8*)(qp + quad * 8);
        qf[qs][1] = *(const short8*)(qp + 32 + quad * 8);
    }

    f32x4 Oacc[2][4];
#pragma unroll
    for (int qs = 0; qs < 2; ++qs)
#pragma unroll
        for (int nt = 0; nt < 4; ++nt) Oacc[qs][nt] = (f32x4){0.f, 0.f, 0.f, 0.f};
    float psum[2][4] = {{0.f, 0.f, 0.f, 0.f}, {0.f, 0.f, 0.f, 0.f}};

    const int fslot = lidx & 7;

    g2l16(kg0,            &Ks[0][lofs]);
    g2l16(kg0 + 8 * 3072, &Ks[0][lofs + 8 * 64]);
    g2l16(vg0,            &Vs[0][lofs]);
    g2l16(vg0 + 8 * 1024, &Vs[0][lofs + 8 * 64]);

    for (int kt = 0; kt < 16; ++kt) {
        __syncthreads();
        const int cur = kt & 1;
        if (kt < 15) {
            const bf16* kg = kg0 + (size_t)(kt + 1) * 64 * 3072;
            const bf16* vg = vg0 + (kt + 1) * 64;
            g2l16(kg,            &Ks[cur ^ 1][lofs]);
            g2l16(kg + 8 * 3072, &Ks[cur ^ 1][lofs + 8 * 64]);
            g2l16(vg,            &Vs[cur ^ 1][lofs]);
            g2l16(vg + 8 * 1024, &Vs[cur ^ 1][lofs + 8 * 64]);
        }

        f32x4 sacc[2][4];
#pragma unroll
        for (int qs = 0; qs < 2; ++qs)
#pragma unroll
            for (int nt = 0; nt < 4; ++nt) sacc[qs][nt] = (f32x4){0.f, 0.f, 0.f, 0.f};
#pragma unroll
        for (int kk = 0; kk < 2; ++kk)
#pragma unroll
            for (int nt = 0; nt < 4; ++nt) {
                short8 kf = *(const short8*)(&Ks[cur][(nt * 16 + lidx) * 64 + (((kk * 4 + quad) ^ fslot) * 8)]);
                sacc[0][nt] = __builtin_amdgcn_mfma_f32_16x16x32_bf16(qf[0][kk], kf, sacc[0][nt], 0, 0, 0);
                sacc[1][nt] = __builtin_amdgcn_mfma_f32_16x16x32_bf16(qf[1][kk], kf, sacc[1][nt], 0, 0, 0);
            }

#pragma unroll
        for (int nt = 0; nt < 4; ++nt) {
            float mv = __bfloat162float(Ms[kt * 64 + nt * 16 + lidx]);
#pragma unroll
            for (int qs = 0; qs < 2; ++qs)
#pragma unroll
                for (int r = 0; r < 4; ++r) {
                    float p = __expf(sacc[qs][nt][r] * 0.125f + mv);
                    sacc[qs][nt][r] = p;
                    psum[qs][r] += p;
                }
        }

#pragma unroll
        for (int qs = 0; qs < 2; ++qs)
#pragma unroll
            for (int nt = 0; nt < 4; ++nt)
#pragma unroll
                for (int r = 0; r < 4; ++r)
                    Ps[wave][(qs * 16 + quad * 4 + r) * PS_LD + nt * 16 + lidx] =
                        __float2bfloat16(sacc[qs][nt][r]);

#pragma unroll
        for (int kk = 0; kk < 2; ++kk) {
            short8 pf0 = *(const short8*)(&Ps[wave][(lidx) * PS_LD + kk * 32 + quad * 8]);
            short8 pf1 = *(const short8*)(&Ps[wave][(16 + lidx) * PS_LD + kk * 32 + quad * 8]);
#pragma unroll
            for (int nt = 0; nt < 4; ++nt) {
                short8 vf = *(const short8*)(&Vs[cur][(nt * 16 + lidx) * 64 + (((kk * 4 + quad) ^ fslot) * 8)]);
                Oacc[0][nt] = __builtin_amdgcn_mfma_f32_16x16x32_bf16(pf0, vf, Oacc[0][nt], 0, 0, 0);
                Oacc[1][nt] = __builtin_amdgcn_mfma_f32_16x16x32_bf16(pf1, vf, Oacc[1][nt], 0, 0, 0);
            }
        }
    }

#pragma unroll
    for (int off = 1; off < 16; off <<= 1)
#pragma unroll
        for (int qs = 0; qs < 2; ++qs)
#pragma unroll
            for (int r = 0; r < 4; ++r)
                psum[qs][r] += __shfl_xor(psum[qs][r], off, 64);
    float linv[2][4];
#pragma unroll
    for (int qs = 0; qs < 2; ++qs)
#pragma unroll
        for (int r = 0; r < 4; ++r) linv[qs][r] = 1.0f / psum[qs][r];

#pragma unroll
    for (int qs = 0; qs < 2; ++qs)
#pragma unroll
        for (int nt = 0; nt < 4; ++nt)
#pragma unroll
            for (int r = 0; r < 4; ++r)
                Ps[wave][(qs * 16 + quad * 4 + r) * PS_LD + nt * 16 + lidx] =
                    __float2bfloat16(Oacc[qs][nt][r] * linv[qs][r]);

    const int row16 = lane >> 2, c4 = lane & 3;
#pragma unroll
    for (int qs = 0; qs < 2; ++qs) {
        bf16* dst = ctx + (size_t)(b * 1024 + q0 + qs * 16 + row16) * 1024 + hh * 64;
        const bf16* srcr = &Ps[wave][(qs * 16 + row16) * PS_LD];
#pragma unroll
        for (int h = 0; h < 2; ++h)
            *(uint4*)(dst + (c4 + 4 * h) * 8) = *(const uint4*)(srcr + (c4 + 4 * h) * 8);
    }
}

// ---------------------------------------------------------------------------
// h = LN(x) * g + b.  x already contains residual+delta (fused in gemm64).
// 2 rows per 512-thread block (halves block count; bit-identical sum order).
// ---------------------------------------------------------------------------
__global__ __launch_bounds__(512) void add_ln_kernel(
    const float* __restrict__ x,
    const float* __restrict__ g, const float* __restrict__ b,
    float* __restrict__ outf, bf16* __restrict__ outb)
{
    __shared__ float red[8];
    const int half = threadIdx.x >> 8;            // 0 or 1: which row
    const int row = blockIdx.x * 2 + half;
    const int t = threadIdx.x & 255;
    const int wv = threadIdx.x >> 6;              // 0..7
    const int rb = half * 4;                      // red base for this row
    const int c0 = t * 4;
    float4 xv = *(const float4*)(x + (size_t)row * 1024 + c0);
    float v[4] = {xv.x, xv.y, xv.z, xv.w};
    float s = v[0] + v[1] + v[2] + v[3];
#pragma unroll
    for (int off = 1; off < 64; off <<= 1) s += __shfl_xor(s, off, 64);
    if ((threadIdx.x & 63) == 0) red[wv] = s;
    __syncthreads();
    float mean = (red[rb] + red[rb + 1] + red[rb + 2] + red[rb + 3]) * (1.0f / 1024.0f);
    float sq = 0.f;
#pragma unroll
    for (int i = 0; i < 4; ++i) { float d = v[i] - mean; sq += d * d; }
#pragma unroll
    for (int off = 1; off < 64; off <<= 1) sq += __shfl_xor(sq, off, 64);
    __syncthreads();
    if ((threadIdx.x & 63) == 0) red[wv] = sq;
    __syncthreads();
    float var = (red[rb] + red[rb + 1] + red[rb + 2] + red[rb + 3]) * (1.0f / 1024.0f);
    float rs = rsqrtf(var + 1e-6f);
    float4 gv = *(const float4*)(g + c0);
    float4 bv = *(const float4*)(b + c0);
    float gg[4] = {gv.x, gv.y, gv.z, gv.w}, bb[4] = {bv.x, bv.y, bv.z, bv.w};
    float o[4];
    unsigned short pk[4];
#pragma unroll
    for (int i = 0; i < 4; ++i) {
        o[i] = (v[i] - mean) * rs * gg[i] + bb[i];
        pk[i] = bf16bits(o[i]);
    }
    *(float4*)(outf + (size_t)row * 1024 + c0) = *(float4*)o;
    *(uint2*)(outb + (size_t)row * 1024 + c0) = *(uint2*)pk;
}

// ---------------------------------------------------------------------------
extern "C" void kernel_launch(void* const* d_in, const int* in_sizes, int n_in,
                              void* d_out, int out_size, void* d_ws, size_t ws_size,
                              hipStream_t stream)
{
    const int*   x    = (const int*)d_in[0];
    const float* mask = (const float*)d_in[1];
    const float* emb  = (const float*)d_in[2];
    const float* wq   = (const float*)d_in[3];
    const float* bq   = (const float*)d_in[4];
    const float* wk   = (const float*)d_in[5];
    const float* bk   = (const float*)d_in[6];
    const float* wv   = (const float*)d_in[7];
    const float* bv   = (const float*)d_in[8];
    const float* wo   = (const float*)d_in[9];
    const float* bo   = (const float*)d_in[10];
    const float* wf   = (const float*)d_in[11];
    const float* bfp  = (const float*)d_in[12];
    const float* g1   = (const float*)d_in[13];
    const float* b1   = (const float*)d_in[14];
    const float* g2   = (const float*)d_in[15];
    const float* b2   = (const float*)d_in[16];

    char* ws = (char*)d_ws;
    float* h_f  = (float*)ws;                 ws += 4096ull * 1024 * 4;   // 16 MB
    bf16*  h_b  = (bf16*)ws;                  ws += 4096ull * 1024 * 2;   //  8 MB
    bf16*  qkv  = (bf16*)ws;                  ws += 4096ull * 3072 * 2;   // 24 MB
    bf16*  vt   = (bf16*)ws;                  ws += 4096ull * 1024 * 2;   //  8 MB
    bf16*  ctx  = (bf16*)ws;                  ws += 4096ull * 1024 * 2;   //  8 MB
    bf16*  wt   = (bf16*)ws;                  ws += 20ull * 1024 * 1024 * 2; // 40 MB
    float* pe   = (float*)ws;                 ws += 1024ull * 1024 * 4;   //  4 MB
    float* bqkv = (float*)ws;                 ws += 4ull * 3072 * 4;
    float* rate = (float*)ws;                 ws += 1024ull * 4;
    float* delta = (float*)qkv;  // fp32 GEMM out, alias of qkv (dead by then)

    wprep_kernel<<<dim3(16, 16, 20), 256, 0, stream>>>(wq, wk, wv, wo, wf, wt);
    bias_stack_kernel<<<dim3(48), 256, 0, stream>>>(bq, bk, bv, bqkv, rate);
    pe_kernel<<<dim3(1024), 256, 0, stream>>>(rate, pe);
    embed_kernel<<<dim3(4096), 256, 0, stream>>>(x, emb, pe, h_f, h_b);

    for (int l = 0; l < 4; ++l) {
        bf16* wt_l = wt + (size_t)l * 5 * 1024 * 1024;
        // QKV: Q,K -> qkv cols [0,2048); V -> vt transposed (fused)
        gemm_bt_kernel<<<dim3(32, 24), 256, 0, stream>>>(
            h_b, wt_l, bqkv + l * 3072, qkv, vt, 4096, 3072, 1024);
        attention_kernel<<<dim3(64, 8), 256, 0, stream>>>(qkv, vt, mask, ctx);
        // delta = ctx@wo + bo + h_f   (residual fused)
        gemm64_kernel<<<dim3(64, 8), 256, 0, stream>>>(
            ctx, wt_l + 3ull * 1024 * 1024, bo + l * 1024, h_f, delta, 4096, 1024, 1024);
        add_ln_kernel<<<dim3(2048), 512, 0, stream>>>(
            delta, g1 + l * 1024, b1 + l * 1024, h_f, h_b);
        // delta = h_b@wf + bf + h_f   (residual fused)
        gemm64_kernel<<<dim3(64, 8), 256, 0, stream>>>(
            h_b, wt_l + 4ull * 1024 * 1024, bfp + l * 1024, h_f, delta, 4096, 1024, 1024);
        float* outf = (l == 3) ? (float*)d_out : h_f;
        add_ln_kernel<<<dim3(2048), 512, 0, stream>>>(
            delta, g2 + l * 1024, b2 + l * 1024, outf, h_b);
    }
    (void)in_sizes; (void)n_in; (void)out_size; (void)ws_size;
}